// Round 4
// baseline (322.956 us; speedup 1.0000x reference)
//
#include <hip/hip_runtime.h>

typedef unsigned short u16;
typedef __attribute__((ext_vector_type(8))) u16 u16x8;
typedef __attribute__((ext_vector_type(8))) __bf16 bf16x8;
typedef __attribute__((ext_vector_type(4))) float f32x4;

// d_out layout (floats): coefs | alpha | new_state | new_buf
#define ALPHA_OFF   3932160
#define NST_OFF     3936256
#define NBUF_OFF    6033408

__device__ __forceinline__ u16 f2bf(float f) {
  unsigned u = __builtin_bit_cast(unsigned, f);
  u += 0x7fffu + ((u >> 16) & 1u);
  return (u16)(u >> 16);
}
__device__ __forceinline__ float bf2f(u16 v) {
  return __builtin_bit_cast(float, (unsigned)v << 16);
}
__device__ __forceinline__ float fsig(float x) { return 1.f / (1.f + __expf(-x)); }
__device__ __forceinline__ float ftanh(float x) {
  x = fminf(15.f, fmaxf(-15.f, x));
  float e = __expf(2.f * x);
  return (e - 1.f) / (e + 1.f);
}
__device__ __forceinline__ f32x4 mfma16(u16x8 a, u16x8 b, f32x4 c) {
  return __builtin_amdgcn_mfma_f32_16x16x32_bf16(
      __builtin_bit_cast(bf16x8, a), __builtin_bit_cast(bf16x8, b), c, 0, 0, 0);
}
__device__ __forceinline__ void gload16(const void* g, void* l) {
  __builtin_amdgcn_global_load_lds(
      (const __attribute__((address_space(1))) void*)g,
      (__attribute__((address_space(3))) void*)l, 16, 0, 0);
}

// ---- K0: merged weight-prep + activation-prep (one dispatch) --------------
// blocks [0,192): W2[L][768][512] bf16 = transpose(concat(gk, grk))
// blocks [192,1216): A0 = [relu(grouped(emb,w_in)) | h0]bf16 ; A1[:,256:] = h1
__global__ __launch_bounds__(256) void prep_all_kernel(
    const float* __restrict__ emb, const float* __restrict__ dec,
    const float* __restrict__ w_in,
    const float* __restrict__ gk0, const float* __restrict__ grk0,
    const float* __restrict__ gk1, const float* __restrict__ grk1,
    u16* __restrict__ A0, u16* __restrict__ A1, u16* __restrict__ W2) {
  int bi = blockIdx.x, tid = threadIdx.x;
  if (bi < 192) {
    // ---- wprep: original grid (12,8,2) flattened bi = nb + 12*kb + 96*L ----
    __shared__ u16 tl[64][65];
    int nb = bi % 12, kb = (bi / 12) % 8, L = bi / 96;
    const float* src = (kb < 4) ? (L ? gk1 : gk0) : (L ? grk1 : grk0);
    int kbase = (kb & 3) * 64;
    u16* dst = W2 + (size_t)L * 768 * 512;
    int c = tid & 63, r4 = tid >> 6;
    for (int rr = 0; rr < 64; rr += 4) {
      int k = kbase + rr + r4, n = nb * 64 + c;
      tl[rr + r4][c] = f2bf(src[(size_t)k * 768 + n]);    // coalesced along n
    }
    __syncthreads();
    for (int rr = 0; rr < 64; rr += 4) {
      int n = nb * 64 + rr + r4, k = kb * 64 + c;
      dst[(size_t)n * 512 + k] = tl[c][rr + r4];          // coalesced along k
    }
  } else {
    // ---- prep: 4 rows/block, weights in registers (L2-hot re-read) ----
    __shared__ float el[4][256];
    int rowBase = (bi - 192) * 4;
    {
      int r = tid >> 6, c4 = tid & 63;
      *(float4*)&el[r][c4 * 4] = ((const float4*)emb)[(size_t)(rowBase + r) * 64 + c4];
    }
    int g = tid >> 5, o = tid & 31;
    float wr[32];
#pragma unroll
    for (int i = 0; i < 32; ++i) wr[i] = w_in[g * 1024 + i * 32 + o];
    __syncthreads();
#pragma unroll
    for (int r = 0; r < 4; ++r) {
      float acc = 0.f;
#pragma unroll
      for (int i = 0; i < 32; ++i) acc += el[r][g * 32 + i] * wr[i];
      A0[(size_t)(rowBase + r) * 512 + tid] = f2bf(fmaxf(acc, 0.f));
    }
    const float4* d4 = (const float4*)dec;
#pragma unroll
    for (int j = 0; j < 2; ++j) {
      int idx = tid + j * 256;               // 512 float4 = 4 rows x 128
      int r = idx >> 7, c4 = idx & 127;
      float4 v = d4[(size_t)(rowBase + r) * 128 + c4];
      ushort4 q;
      q.x = f2bf(v.x); q.y = f2bf(v.y); q.z = f2bf(v.z); q.w = f2bf(v.w);
      u16* dst = (c4 < 64) ? A0 + (size_t)(rowBase + r) * 512 + 256 + c4 * 4
                           : A1 + (size_t)(rowBase + r) * 512 + 256 + (c4 - 64) * 4;
      *(ushort4*)dst = q;
    }
  }
}

// ---- K1/K2: GRU layer as MFMA GEMM, fused gate epilogue -------------------
// 32 rows x 64 cols/gate per block; grid (128,4) = 512 blocks = 2/CU.
template <int LAYER>
__global__ __launch_bounds__(256) void gru_kernel(
    const u16* __restrict__ Ain,    // [4096][512] bf16
    const u16* __restrict__ W2,     // [768][512] bf16
    const float* __restrict__ dec,
    const float* __restrict__ bias, // [2][768]
    float* __restrict__ nst,        // d_out+NST_OFF [4096][512]
    u16* __restrict__ a1out,        // LAYER0: A1 cols 0-255
    const u16* __restrict__ xbf,    // LAYER1: A0 (x in cols 0-255)
    u16* __restrict__ c_bf) {       // LAYER1: [4096][256] bf16
  __shared__ __align__(16) u16 lsA[2][32][32];
  __shared__ __align__(16) u16 lsB[2][3][64][32];
  int tid = threadIdx.x, lane = tid & 63, wave = tid >> 6;
  int m0 = lane & 15, quad = lane >> 4;
  int rowBase = blockIdx.x * 32, jz = blockIdx.y * 64, cw = wave * 16;
  f32x4 acc[4][2];
#pragma unroll
  for (int gi = 0; gi < 4; ++gi)
#pragma unroll
    for (int rb = 0; rb < 2; ++rb) acc[gi][rb] = (f32x4){0.f, 0.f, 0.f, 0.f};

  int rS = tid >> 2, qS = tid & 3;
  auto stage = [&](int buf, int k0) {
    if (tid < 128)
      gload16(Ain + (size_t)(rowBase + rS) * 512 + k0 + qS * 8,
              &lsA[buf][rS][qS * 8]);
#pragma unroll
    for (int g = 0; g < 3; ++g)
      gload16(W2 + (size_t)(g * 256 + jz + rS) * 512 + k0 + qS * 8,
              &lsB[buf][g][rS][qS * 8]);
  };

  stage(0, 0);
  for (int step = 0; step < 16; ++step) {
    __syncthreads();
    if (step < 15) stage((step & 1) ^ 1, (step + 1) * 32);
    int cur = step & 1;
    u16x8 av[2], bv[3];
#pragma unroll
    for (int rb = 0; rb < 2; ++rb)
      av[rb] = *(const u16x8*)&lsA[cur][rb * 16 + m0][quad * 8];
#pragma unroll
    for (int g = 0; g < 3; ++g)
      bv[g] = *(const u16x8*)&lsB[cur][g][cw + m0][quad * 8];
#pragma unroll
    for (int rb = 0; rb < 2; ++rb) {
      acc[0][rb] = mfma16(av[rb], bv[0], acc[0][rb]);
      acc[1][rb] = mfma16(av[rb], bv[1], acc[1][rb]);
    }
    if (step < 8) {
#pragma unroll
      for (int rb = 0; rb < 2; ++rb) acc[2][rb] = mfma16(av[rb], bv[2], acc[2][rb]);
    } else {
#pragma unroll
      for (int rb = 0; rb < 2; ++rb) acc[3][rb] = mfma16(av[rb], bv[2], acc[3][rb]);
    }
  }

  int col = jz + cw + m0;
  float bz = bias[col] + bias[768 + col];
  float br = bias[256 + col] + bias[1024 + col];
  float bxh = bias[512 + col];
  float bhh = bias[1280 + col];
  const int hoff = LAYER ? 256 : 0;
#pragma unroll
  for (int rb = 0; rb < 2; ++rb) {
#pragma unroll
    for (int i = 0; i < 4; ++i) {
      int row = rowBase + rb * 16 + quad * 4 + i;  // C/D: col=lane&15,row=quad*4+reg
      float h = dec[(size_t)row * 512 + hoff + col];
      float z = fsig(acc[0][rb][i] + bz);
      float r = fsig(acc[1][rb][i] + br);
      float cand = ftanh(acc[2][rb][i] + bxh + r * (acc[3][rb][i] + bhh));
      float o = z * h + (1.f - z) * cand;
      nst[(size_t)row * 512 + hoff + col] = o;
      if (LAYER == 0) {
        a1out[(size_t)row * 512 + col] = f2bf(o);
      } else {
        float c = o + bf2f(xbf[(size_t)row * 512 + col]);
        c_bf[(size_t)row * 256 + col] = f2bf(c);
      }
    }
  }
}

// ---- K3: fused head: conv+pw+BN+relu + tanh(grouped(c,w_out)) + alpha -----
// 1 row/block, 192 threads. v3: w_out matvec fused in (wout_kernel removed):
// threads 0..119 each produce 8 consecutive outputs of the 960-wide grouped
// matvec (float4-aligned weight loads, L2-resident 123 KB weight set),
// eliminating the 15.7 MB coefs pre-write + 15.7 MB scattered re-read.
__global__ __launch_bounds__(192) void head_kernel(
    const float* __restrict__ convp, const float* __restrict__ c0,
    const u16* __restrict__ c_bf,
    const float* __restrict__ conv_w, const float* __restrict__ pw_w,
    const float* __restrict__ bng, const float* __restrict__ bnb,
    const float* __restrict__ bnm, const float* __restrict__ bnv,
    const float* __restrict__ fca_w, const float* __restrict__ fca_b,
    const float* __restrict__ w_out,
    float* __restrict__ outp) {
  __shared__ __align__(16) float cw2[640];   // [t][i][half][8] (5 live of 8)
  __shared__ float pws[100];
  __shared__ float bsc[10], bsh[10];
  __shared__ float ybuf[96][11];
  __shared__ float ared[3];
  __shared__ float cl[8][33];                // c row, padded vs 32-bank alias
  int tid = threadIdx.x, lane = tid & 63, wave = tid >> 6;
  int b = blockIdx.x;
  int f = tid >> 1, half = tid & 1;
  const float4* cp4 = (const float4*)convp;
  const float4* c04 = (const float4*)c0;
  float4* nb4 = (float4*)(outp + NBUF_OFF);

  // ---- front-issue all global reads ----
  size_t sbase = (size_t)b * 1536 + f * 4 + half * 2;
  size_t cbase = (size_t)b * 384 + f * 4 + half * 2;
  float4 xa0 = cp4[sbase];         float4 xb0 = cp4[sbase + 1];
  float4 xa1 = cp4[sbase + 384];   float4 xb1 = cp4[sbase + 385];
  float4 xa2 = cp4[sbase + 768];   float4 xb2 = cp4[sbase + 769];
  float4 xa3 = cp4[sbase + 1152];  float4 xb3 = cp4[sbase + 1153];
  float4 xa4 = c04[cbase];         float4 xb4 = c04[cbase + 1];
  // ---- c row -> LDS + alpha partial ----
  float cv = bf2f(c_bf[(size_t)b * 256 + tid]);
  cl[tid >> 5][tid & 31] = cv;
  float ap = cv * fca_w[tid];
  if (tid < 64) {
    float cv2 = bf2f(c_bf[(size_t)b * 256 + 192 + tid]);
    cl[(192 + tid) >> 5][tid & 31] = cv2;
    ap += cv2 * fca_w[192 + tid];
  }

  // ---- constants to LDS (conv weights repacked for vector reads) ----
  for (int i = tid; i < 400; i += 192) {
    int t = i / 80, rr = (i % 80) / 10, h = (i % 10) / 5, j = i % 5;
    cw2[((t * 8 + rr) * 2 + h) * 8 + j] = conv_w[i];
  }
  if (tid < 100) pws[tid] = pw_w[tid];
  if (tid < 10) {
    float s = bng[tid] * rsqrtf(bnv[tid] + 1e-3f);
    bsc[tid] = s;
    bsh[tid] = bnb[tid] - bnm[tid] * s;
  }
  // ---- new_buf copy from registers ----
  nb4[sbase] = xa1;         nb4[sbase + 1] = xb1;
  nb4[sbase + 384] = xa2;   nb4[sbase + 385] = xb2;
  nb4[sbase + 768] = xa3;   nb4[sbase + 769] = xb3;
  nb4[sbase + 1152] = xa4;  nb4[sbase + 1153] = xb4;
  // ---- alpha partial ----
#pragma unroll
  for (int off = 32; off > 0; off >>= 1) ap += __shfl_down(ap, off, 64);
  if (lane == 0) ared[wave] = ap;
  __syncthreads();                       // cl, cw2, pws, bsc ready

  // ---- fused w_out matvec: 120 threads x 8 consecutive outputs ----
  float a8[8] = {0.f, 0.f, 0.f, 0.f, 0.f, 0.f, 0.f, 0.f};
  int gg = 0, o0 = 0;
  if (tid < 120) {
    gg = tid / 15; o0 = (tid % 15) * 8;  // byte offset 32-aligned for float4
    const float* wp = w_out + (size_t)gg * 3840 + o0;
#pragma unroll
    for (int k = 0; k < 32; ++k) {
      float ck = cl[gg][k];
      float4 wA = *(const float4*)(wp + k * 120);
      float4 wB = *(const float4*)(wp + k * 120 + 4);
      a8[0] += ck * wA.x; a8[1] += ck * wA.y;
      a8[2] += ck * wA.z; a8[3] += ck * wA.w;
      a8[4] += ck * wB.x; a8[5] += ck * wB.y;
      a8[6] += ck * wB.z; a8[7] += ck * wB.w;
    }
  }

  // ---- grouped depth conv (fp32, regs; fully static indexing) ----
  float a5[5] = {0.f, 0.f, 0.f, 0.f, 0.f};
#define CI(XF, T, I)                                                        \
  {                                                                         \
    const float* wp = &cw2[(((T) * 8 + (I)) * 2 + half) * 8];               \
    float4 w03 = *(const float4*)wp;                                        \
    float w4 = wp[4];                                                       \
    a5[0] += (XF) * w03.x; a5[1] += (XF) * w03.y; a5[2] += (XF) * w03.z;    \
    a5[3] += (XF) * w03.w; a5[4] += (XF) * w4;                              \
  }
#define CTAP(VA, VB, T)                                                     \
  CI(VA.x, T, 0) CI(VA.y, T, 1) CI(VA.z, T, 2) CI(VA.w, T, 3)               \
  CI(VB.x, T, 4) CI(VB.y, T, 5) CI(VB.z, T, 6) CI(VB.w, T, 7)
  CTAP(xa0, xb0, 0)
  CTAP(xa1, xb1, 1)
  CTAP(xa2, xb2, 2)
  CTAP(xa3, xb3, 3)
  CTAP(xa4, xb4, 4)
#undef CTAP
#undef CI
#pragma unroll
  for (int j = 0; j < 5; ++j) ybuf[f][half * 5 + j] = a5[j];
  __syncthreads();
  if (tid == 0)
    outp[ALPHA_OFF + b] = fsig(ared[0] + ared[1] + ared[2] + fca_b[0]);
  // ---- pw + BN + relu + add tanh term; write final coefs layout ----
  if (tid < 120) {
#pragma unroll
    for (int m = 0; m < 8; ++m) {
      int e = gg * 120 + o0 + m;           // flat index f*10+p
      int ff = e / 10, p = e % 10;
      float y2 = 0.f;
#pragma unroll
      for (int j = 0; j < 10; ++j) y2 += ybuf[ff][j] * pws[j * 10 + p];
      float v = fmaxf(y2 * bsc[p] + bsh[p], 0.f) + ftanh(a8[m]);
      outp[(size_t)b * 960 + (p >> 1) * 192 + ff * 2 + (p & 1)] = v;
    }
  }
}

// ---------------------------------------------------------------------------
extern "C" void kernel_launch(void* const* d_in, const int* in_sizes, int n_in,
                              void* d_out, int out_size, void* d_ws, size_t ws_size,
                              hipStream_t stream) {
  const float* emb    = (const float*)d_in[0];
  const float* c0     = (const float*)d_in[1];
  const float* dec    = (const float*)d_in[2];
  const float* convp  = (const float*)d_in[3];
  const float* w_in   = (const float*)d_in[4];
  const float* gk0    = (const float*)d_in[5];
  const float* grk0   = (const float*)d_in[6];
  const float* gb0    = (const float*)d_in[7];
  const float* gk1    = (const float*)d_in[8];
  const float* grk1   = (const float*)d_in[9];
  const float* gb1    = (const float*)d_in[10];
  const float* w_out  = (const float*)d_in[11];
  const float* fca_w  = (const float*)d_in[12];
  const float* fca_b  = (const float*)d_in[13];
  const float* conv_w = (const float*)d_in[14];
  const float* pw_w   = (const float*)d_in[15];
  const float* bng    = (const float*)d_in[16];
  const float* bnb    = (const float*)d_in[17];
  const float* bnm    = (const float*)d_in[18];
  const float* bnv    = (const float*)d_in[19];
  float* out = (float*)d_out;
  char* ws = (char*)d_ws;
  u16* A0   = (u16*)(ws + 0);            // [4096][512] bf16, 4 MB
  u16* A1   = (u16*)(ws + 4194304);      // [4096][512] bf16, 4 MB
  u16* c_bf = (u16*)(ws + 8388608);      // [4096][256] bf16, 2 MB
  u16* W2   = (u16*)(ws + 10485760);     // [2][768][512] bf16, 1.5 MB

  prep_all_kernel<<<dim3(1216), 256, 0, stream>>>(emb, dec, w_in,
                                                  gk0, grk0, gk1, grk1,
                                                  A0, A1, W2);
  gru_kernel<0><<<dim3(128, 4), 256, 0, stream>>>(A0, W2, dec, gb0,
                                                  out + NST_OFF, A1, nullptr, nullptr);
  gru_kernel<1><<<dim3(128, 4), 256, 0, stream>>>(A1, W2 + 768 * 512, dec, gb1,
                                                  out + NST_OFF, nullptr, A0, c_bf);
  head_kernel<<<dim3(4096), 192, 0, stream>>>(convp, c0, c_bf, conv_w, pw_w,
                                              bng, bnb, bnm, bnv, fca_w, fca_b,
                                              w_out, out);
}

// Round 7
// 307.032 us; speedup vs baseline: 1.0519x; 1.0519x over previous
//
#include <hip/hip_runtime.h>

typedef unsigned short u16;
typedef __attribute__((ext_vector_type(8))) u16 u16x8;
typedef __attribute__((ext_vector_type(8))) __bf16 bf16x8;
typedef __attribute__((ext_vector_type(4))) float f32x4;

// d_out layout (floats): coefs | alpha | new_state | new_buf
#define ALPHA_OFF   3932160
#define NST_OFF     3936256
#define NBUF_OFF    6033408

__device__ __forceinline__ u16 f2bf(float f) {
  unsigned u = __builtin_bit_cast(unsigned, f);
  u += 0x7fffu + ((u >> 16) & 1u);
  return (u16)(u >> 16);
}
__device__ __forceinline__ float bf2f(u16 v) {
  return __builtin_bit_cast(float, (unsigned)v << 16);
}
__device__ __forceinline__ float fsig(float x) { return 1.f / (1.f + __expf(-x)); }
__device__ __forceinline__ float ftanh(float x) {
  x = fminf(15.f, fmaxf(-15.f, x));
  float e = __expf(2.f * x);
  return (e - 1.f) / (e + 1.f);
}
__device__ __forceinline__ f32x4 mfma16(u16x8 a, u16x8 b, f32x4 c) {
  return __builtin_amdgcn_mfma_f32_16x16x32_bf16(
      __builtin_bit_cast(bf16x8, a), __builtin_bit_cast(bf16x8, b), c, 0, 0, 0);
}
__device__ __forceinline__ void gload16(const void* g, void* l) {
  __builtin_amdgcn_global_load_lds(
      (const __attribute__((address_space(1))) void*)g,
      (__attribute__((address_space(3))) void*)l, 16, 0, 0);
}

// ---- K0: merged weight-prep + w3prep + activation-prep (one dispatch) -----
// blocks [0,192): W2[L][768][512] bf16 = transpose(concat(gk, grk))
// blocks [192,200): W3[8][128][32] bf16 = w_out transposed, zero-pad
// blocks [200,1224): A0 = [relu(grouped(emb,w_in)) | h0]bf16 ; A1[:,256:] = h1
__global__ __launch_bounds__(256) void prep_all_kernel(
    const float* __restrict__ emb, const float* __restrict__ dec,
    const float* __restrict__ w_in,
    const float* __restrict__ gk0, const float* __restrict__ grk0,
    const float* __restrict__ gk1, const float* __restrict__ grk1,
    const float* __restrict__ w_out,
    u16* __restrict__ A0, u16* __restrict__ A1, u16* __restrict__ W2,
    u16* __restrict__ W3) {
  int bi = blockIdx.x, tid = threadIdx.x;
  if (bi < 192) {
    // ---- wprep: original grid (12,8,2) flattened bi = nb + 12*kb + 96*L ----
    __shared__ u16 tl[64][65];
    int nb = bi % 12, kb = (bi / 12) % 8, L = bi / 96;
    const float* src = (kb < 4) ? (L ? gk1 : gk0) : (L ? grk1 : grk0);
    int kbase = (kb & 3) * 64;
    u16* dst = W2 + (size_t)L * 768 * 512;
    int c = tid & 63, r4 = tid >> 6;
    for (int rr = 0; rr < 64; rr += 4) {
      int k = kbase + rr + r4, n = nb * 64 + c;
      tl[rr + r4][c] = f2bf(src[(size_t)k * 768 + n]);    // coalesced along n
    }
    __syncthreads();
    for (int rr = 0; rr < 64; rr += 4) {
      int n = nb * 64 + rr + r4, k = kb * 64 + c;
      dst[(size_t)n * 512 + k] = tl[c][rr + r4];          // coalesced along k
    }
  } else if (bi < 200) {
    // ---- w3prep ----
    int g = bi - 192;
    for (int i = tid; i < 4096; i += 256) {
      int col = i >> 5, k = i & 31;
      float v = (col < 120) ? w_out[(size_t)g * 3840 + k * 120 + col] : 0.f;
      W3[(size_t)g * 4096 + i] = f2bf(v);
    }
  } else {
    // ---- prep: 4 rows/block, weights in registers (L2-hot re-read) ----
    __shared__ float el[4][256];
    int rowBase = (bi - 200) * 4;
    {
      int r = tid >> 6, c4 = tid & 63;
      *(float4*)&el[r][c4 * 4] = ((const float4*)emb)[(size_t)(rowBase + r) * 64 + c4];
    }
    int g = tid >> 5, o = tid & 31;
    float wr[32];
#pragma unroll
    for (int i = 0; i < 32; ++i) wr[i] = w_in[g * 1024 + i * 32 + o];
    __syncthreads();
#pragma unroll
    for (int r = 0; r < 4; ++r) {
      float acc = 0.f;
#pragma unroll
      for (int i = 0; i < 32; ++i) acc += el[r][g * 32 + i] * wr[i];
      A0[(size_t)(rowBase + r) * 512 + tid] = f2bf(fmaxf(acc, 0.f));
    }
    const float4* d4 = (const float4*)dec;
#pragma unroll
    for (int j = 0; j < 2; ++j) {
      int idx = tid + j * 256;               // 512 float4 = 4 rows x 128
      int r = idx >> 7, c4 = idx & 127;
      float4 v = d4[(size_t)(rowBase + r) * 128 + c4];
      ushort4 q;
      q.x = f2bf(v.x); q.y = f2bf(v.y); q.z = f2bf(v.z); q.w = f2bf(v.w);
      u16* dst = (c4 < 64) ? A0 + (size_t)(rowBase + r) * 512 + 256 + c4 * 4
                           : A1 + (size_t)(rowBase + r) * 512 + 256 + (c4 - 64) * 4;
      *(ushort4*)dst = q;
    }
  }
}

// ---- K1/K2: GRU layer as MFMA GEMM, fused gate epilogue -------------------
// 32 rows x 64 cols/gate per block; grid (128,4) = 512 blocks = 2/CU.
template <int LAYER>
__global__ __launch_bounds__(256) void gru_kernel(
    const u16* __restrict__ Ain,    // [4096][512] bf16
    const u16* __restrict__ W2,     // [768][512] bf16
    const float* __restrict__ dec,
    const float* __restrict__ bias, // [2][768]
    float* __restrict__ nst,        // d_out+NST_OFF [4096][512]
    u16* __restrict__ a1out,        // LAYER0: A1 cols 0-255
    const u16* __restrict__ xbf,    // LAYER1: A0 (x in cols 0-255)
    u16* __restrict__ c_bf) {       // LAYER1: [4096][256] bf16
  __shared__ __align__(16) u16 lsA[2][32][32];
  __shared__ __align__(16) u16 lsB[2][3][64][32];
  int tid = threadIdx.x, lane = tid & 63, wave = tid >> 6;
  int m0 = lane & 15, quad = lane >> 4;
  int rowBase = blockIdx.x * 32, jz = blockIdx.y * 64, cw = wave * 16;
  f32x4 acc[4][2];
#pragma unroll
  for (int gi = 0; gi < 4; ++gi)
#pragma unroll
    for (int rb = 0; rb < 2; ++rb) acc[gi][rb] = (f32x4){0.f, 0.f, 0.f, 0.f};

  int rS = tid >> 2, qS = tid & 3;
  auto stage = [&](int buf, int k0) {
    if (tid < 128)
      gload16(Ain + (size_t)(rowBase + rS) * 512 + k0 + qS * 8,
              &lsA[buf][rS][qS * 8]);
#pragma unroll
    for (int g = 0; g < 3; ++g)
      gload16(W2 + (size_t)(g * 256 + jz + rS) * 512 + k0 + qS * 8,
              &lsB[buf][g][rS][qS * 8]);
  };

  stage(0, 0);
  for (int step = 0; step < 16; ++step) {
    __syncthreads();
    if (step < 15) stage((step & 1) ^ 1, (step + 1) * 32);
    int cur = step & 1;
    u16x8 av[2], bv[3];
#pragma unroll
    for (int rb = 0; rb < 2; ++rb)
      av[rb] = *(const u16x8*)&lsA[cur][rb * 16 + m0][quad * 8];
#pragma unroll
    for (int g = 0; g < 3; ++g)
      bv[g] = *(const u16x8*)&lsB[cur][g][cw + m0][quad * 8];
#pragma unroll
    for (int rb = 0; rb < 2; ++rb) {
      acc[0][rb] = mfma16(av[rb], bv[0], acc[0][rb]);
      acc[1][rb] = mfma16(av[rb], bv[1], acc[1][rb]);
    }
    if (step < 8) {
#pragma unroll
      for (int rb = 0; rb < 2; ++rb) acc[2][rb] = mfma16(av[rb], bv[2], acc[2][rb]);
    } else {
#pragma unroll
      for (int rb = 0; rb < 2; ++rb) acc[3][rb] = mfma16(av[rb], bv[2], acc[3][rb]);
    }
  }

  int col = jz + cw + m0;
  float bz = bias[col] + bias[768 + col];
  float br = bias[256 + col] + bias[1024 + col];
  float bxh = bias[512 + col];
  float bhh = bias[1280 + col];
  const int hoff = LAYER ? 256 : 0;
#pragma unroll
  for (int rb = 0; rb < 2; ++rb) {
#pragma unroll
    for (int i = 0; i < 4; ++i) {
      int row = rowBase + rb * 16 + quad * 4 + i;  // C/D: col=lane&15,row=quad*4+reg
      float h = dec[(size_t)row * 512 + hoff + col];
      float z = fsig(acc[0][rb][i] + bz);
      float r = fsig(acc[1][rb][i] + br);
      float cand = ftanh(acc[2][rb][i] + bxh + r * (acc[3][rb][i] + bhh));
      float o = z * h + (1.f - z) * cand;
      nst[(size_t)row * 512 + hoff + col] = o;
      if (LAYER == 0) {
        a1out[(size_t)row * 512 + col] = f2bf(o);
      } else {
        float c = o + bf2f(xbf[(size_t)row * 512 + col]);
        c_bf[(size_t)row * 256 + col] = f2bf(c);
      }
    }
  }
}

// ---- K3: temp = tanh(grouped(c,w_out)) via MFMA, stored in FINAL layout ---
// Block: 64 rows x 1 group (128 cols, 120 live). Grid (64, 8).
// v4: writes into outp coefs region at the FINAL index so head's read+write
// are both fully coalesced (scatter moved to the store side).
__global__ __launch_bounds__(256) void wout_kernel(
    const u16* __restrict__ c_bf, const u16* __restrict__ W3,
    float* __restrict__ outc) {
  __shared__ __align__(16) u16 lsA[64][32];
  __shared__ __align__(16) u16 lsB[128][32];
  int tid = threadIdx.x, lane = tid & 63, wave = tid >> 6;
  int m0 = lane & 15, quad = lane >> 4;
  int rowBase = blockIdx.x * 64, g = blockIdx.y;
  {
    int r = tid >> 2, q = tid & 3;
    gload16(c_bf + (size_t)(rowBase + r) * 256 + g * 32 + q * 8, &lsA[r][q * 8]);
    gload16(W3 + (size_t)g * 4096 + (size_t)r * 32 + q * 8, &lsB[r][q * 8]);
    gload16(W3 + (size_t)g * 4096 + (size_t)(64 + r) * 32 + q * 8, &lsB[64 + r][q * 8]);
  }
  __syncthreads();
  int cw = wave * 32;
  f32x4 acc[4][2];
#pragma unroll
  for (int rb = 0; rb < 4; ++rb)
#pragma unroll
    for (int cb = 0; cb < 2; ++cb) acc[rb][cb] = (f32x4){0.f, 0.f, 0.f, 0.f};
  u16x8 bv[2];
#pragma unroll
  for (int cb = 0; cb < 2; ++cb)
    bv[cb] = *(const u16x8*)&lsB[cw + cb * 16 + m0][quad * 8];
#pragma unroll
  for (int rb = 0; rb < 4; ++rb) {
    u16x8 av = *(const u16x8*)&lsA[rb * 16 + m0][quad * 8];
#pragma unroll
    for (int cb = 0; cb < 2; ++cb) acc[rb][cb] = mfma16(av, bv[cb], acc[rb][cb]);
  }
#pragma unroll
  for (int cb = 0; cb < 2; ++cb) {
    int cg = cw + cb * 16 + m0;
    if (cg < 120) {
      int e0 = g * 120 + cg;                 // flat (f*10+p)
      int ff = e0 / 10, p = e0 % 10;
      int fin = (p >> 1) * 192 + ff * 2 + (p & 1);
#pragma unroll
      for (int rb = 0; rb < 4; ++rb)
#pragma unroll
        for (int i = 0; i < 4; ++i)
          outc[(size_t)(rowBase + rb * 16 + quad * 4 + i) * 960 + fin] =
              ftanh(acc[rb][cb][i]);
    }
  }
}

// ---- K4: head: conv+pw+BN+relu + combine + alpha + new_buf ----------------
// v4: 384 threads = 2 rows/block (2048 blocks): 2x loads-in-flight per CU,
// half the dispatch count. tmp read + coefs write fully coalesced (wout
// pre-writes tanh term in final layout).
__global__ __launch_bounds__(384) void head_kernel(
    const float* __restrict__ convp, const float* __restrict__ c0,
    const u16* __restrict__ c_bf,
    const float* __restrict__ conv_w, const float* __restrict__ pw_w,
    const float* __restrict__ bng, const float* __restrict__ bnb,
    const float* __restrict__ bnm, const float* __restrict__ bnv,
    const float* __restrict__ fca_w, const float* __restrict__ fca_b,
    float* __restrict__ outp) {
  __shared__ __align__(16) float cw2[640];   // [t][i][half][8] (5 live of 8)
  __shared__ float pws[100];
  __shared__ float bsc[10], bsh[10];
  __shared__ float ybuf[2][96][11];
  __shared__ float ared[6];
  int tid = threadIdx.x, lane = tid & 63, wave = tid >> 6;
  int row = tid >= 192, t = tid - row * 192;
  int brow = blockIdx.x * 2 + row;
  int f = t >> 1, half = t & 1;
  const float4* cp4 = (const float4*)convp;
  const float4* c04 = (const float4*)c0;
  float4* nb4 = (float4*)(outp + NBUF_OFF);

  // ---- front-issue all global reads (named vars -> stay in VGPRs) ----
  size_t sbase = (size_t)brow * 1536 + f * 4 + half * 2;
  size_t cbase = (size_t)brow * 384 + f * 4 + half * 2;
  float4 xa0 = cp4[sbase];         float4 xb0 = cp4[sbase + 1];
  float4 xa1 = cp4[sbase + 384];   float4 xb1 = cp4[sbase + 385];
  float4 xa2 = cp4[sbase + 768];   float4 xb2 = cp4[sbase + 769];
  float4 xa3 = cp4[sbase + 1152];  float4 xb3 = cp4[sbase + 1153];
  float4 xa4 = c04[cbase];         float4 xb4 = c04[cbase + 1];
  float tmp[5];
#pragma unroll
  for (int k = 0; k < 5; ++k)                // coalesced: wout wrote final layout
    tmp[k] = outp[(size_t)brow * 960 + t + k * 192];
  float ap = bf2f(c_bf[(size_t)brow * 256 + t]) * fca_w[t];
  if (t < 64) ap += bf2f(c_bf[(size_t)brow * 256 + 192 + t]) * fca_w[192 + t];

  // ---- constants to LDS (conv weights repacked for vector reads) ----
  for (int i = tid; i < 400; i += 384) {
    int tt = i / 80, rr = (i % 80) / 10, h = (i % 10) / 5, j = i % 5;
    cw2[((tt * 8 + rr) * 2 + h) * 8 + j] = conv_w[i];
  }
  if (tid < 100) pws[tid] = pw_w[tid];
  if (tid < 10) {
    float s = bng[tid] * rsqrtf(bnv[tid] + 1e-3f);
    bsc[tid] = s;
    bsh[tid] = bnb[tid] - bnm[tid] * s;
  }
  // ---- new_buf copy from registers ----
  nb4[sbase] = xa1;         nb4[sbase + 1] = xb1;
  nb4[sbase + 384] = xa2;   nb4[sbase + 385] = xb2;
  nb4[sbase + 768] = xa3;   nb4[sbase + 769] = xb3;
  nb4[sbase + 1152] = xa4;  nb4[sbase + 1153] = xb4;
  // ---- alpha partial (waves 0-2 row0, waves 3-5 row1) ----
#pragma unroll
  for (int off = 32; off > 0; off >>= 1) ap += __shfl_down(ap, off, 64);
  if (lane == 0) ared[wave] = ap;
  __syncthreads();
  // ---- grouped depth conv (fp32, regs; fully static indexing) ----
  float a5[5] = {0.f, 0.f, 0.f, 0.f, 0.f};
#define CI(XF, T, I)                                                        \
  {                                                                         \
    const float* wp = &cw2[(((T) * 8 + (I)) * 2 + half) * 8];               \
    float4 w03 = *(const float4*)wp;                                        \
    float w4 = wp[4];                                                       \
    a5[0] += (XF) * w03.x; a5[1] += (XF) * w03.y; a5[2] += (XF) * w03.z;    \
    a5[3] += (XF) * w03.w; a5[4] += (XF) * w4;                              \
  }
#define CTAP(VA, VB, T)                                                     \
  CI(VA.x, T, 0) CI(VA.y, T, 1) CI(VA.z, T, 2) CI(VA.w, T, 3)               \
  CI(VB.x, T, 4) CI(VB.y, T, 5) CI(VB.z, T, 6) CI(VB.w, T, 7)
  CTAP(xa0, xb0, 0)
  CTAP(xa1, xb1, 1)
  CTAP(xa2, xb2, 2)
  CTAP(xa3, xb3, 3)
  CTAP(xa4, xb4, 4)
#undef CTAP
#undef CI
#pragma unroll
  for (int j = 0; j < 5; ++j) ybuf[row][f][half * 5 + j] = a5[j];
  __syncthreads();
  if (t == 0)
    outp[ALPHA_OFF + brow] =
        fsig(ared[row * 3] + ared[row * 3 + 1] + ared[row * 3 + 2] + fca_b[0]);
  // ---- pw + BN + relu + add tanh term; coalesced final write --------------
  // element u = t + k*192 in final layout == (ff=f, p=2k+half)
  float vals[5];
#pragma unroll
  for (int k = 0; k < 5; ++k) {
    int p = k * 2 + half;
    float y2 = 0.f;
#pragma unroll
    for (int j = 0; j < 10; ++j) y2 += ybuf[row][f][j] * pws[j * 10 + p];
    vals[k] = fmaxf(y2 * bsc[p] + bsh[p], 0.f) + tmp[k];
  }
#pragma unroll
  for (int k = 0; k < 5; ++k)
    outp[(size_t)brow * 960 + t + k * 192] = vals[k];
}

// ---------------------------------------------------------------------------
extern "C" void kernel_launch(void* const* d_in, const int* in_sizes, int n_in,
                              void* d_out, int out_size, void* d_ws, size_t ws_size,
                              hipStream_t stream) {
  const float* emb    = (const float*)d_in[0];
  const float* c0     = (const float*)d_in[1];
  const float* dec    = (const float*)d_in[2];
  const float* convp  = (const float*)d_in[3];
  const float* w_in   = (const float*)d_in[4];
  const float* gk0    = (const float*)d_in[5];
  const float* grk0   = (const float*)d_in[6];
  const float* gb0    = (const float*)d_in[7];
  const float* gk1    = (const float*)d_in[8];
  const float* grk1   = (const float*)d_in[9];
  const float* gb1    = (const float*)d_in[10];
  const float* w_out  = (const float*)d_in[11];
  const float* fca_w  = (const float*)d_in[12];
  const float* fca_b  = (const float*)d_in[13];
  const float* conv_w = (const float*)d_in[14];
  const float* pw_w   = (const float*)d_in[15];
  const float* bng    = (const float*)d_in[16];
  const float* bnb    = (const float*)d_in[17];
  const float* bnm    = (const float*)d_in[18];
  const float* bnv    = (const float*)d_in[19];
  float* out = (float*)d_out;
  char* ws = (char*)d_ws;
  u16* A0   = (u16*)(ws + 0);            // [4096][512] bf16, 4 MB
  u16* A1   = (u16*)(ws + 4194304);      // [4096][512] bf16, 4 MB
  u16* c_bf = (u16*)(ws + 8388608);      // [4096][256] bf16, 2 MB
  u16* W2   = (u16*)(ws + 10485760);     // [2][768][512] bf16, 1.5 MB
  u16* W3   = (u16*)(ws + 12058624);     // [8][128][32] bf16, 64 KB

  prep_all_kernel<<<dim3(1224), 256, 0, stream>>>(emb, dec, w_in,
                                                  gk0, grk0, gk1, grk1, w_out,
                                                  A0, A1, W2, W3);
  gru_kernel<0><<<dim3(128, 4), 256, 0, stream>>>(A0, W2, dec, gb0,
                                                  out + NST_OFF, A1, nullptr, nullptr);
  gru_kernel<1><<<dim3(128, 4), 256, 0, stream>>>(A1, W2 + 768 * 512, dec, gb1,
                                                  out + NST_OFF, nullptr, A0, c_bf);
  wout_kernel<<<dim3(64, 8), 256, 0, stream>>>(c_bf, W3, out);
  head_kernel<<<dim3(2048), 384, 0, stream>>>(convp, c0, c_bf, conv_w, pw_w,
                                              bng, bnb, bnm, bnv, fca_w, fca_b, out);
}